// Round 7
// baseline (315.676 us; speedup 1.0000x reference)
//
#include <hip/hip_runtime.h>

#define NNODES 50000
#define NEDGES 1600000
#define F 128

#define NB 128        // coarse buckets
#define BSH 391       // nodes per bucket (128*391 = 50048 >= 50000)
#define BCAP 13312    // slots per bucket (mean 12500, +7 sigma)
#define EPT 10        // edges per thread in bucketA (625 * 2560 = 1600000 exactly)

typedef __attribute__((ext_vector_type(8))) short bf16x8;
typedef __attribute__((ext_vector_type(4))) float f32x4;

__device__ inline unsigned short f2bf(float f) {
    union { float f; unsigned u; } v; v.f = f;
    unsigned r = v.u + 0x7FFF + ((v.u >> 16) & 1);  // RNE
    return (unsigned short)(r >> 16);
}
__device__ inline float b2f(unsigned short h) {
    union { unsigned u; float f; } a;
    a.u = ((unsigned)h) << 16;
    return a.f;
}

// ---------------- f32 -> bf16 feature conversion ----------------
__global__ __launch_bounds__(256) void cvt_bf16(const float4* __restrict__ in,
                                                ushort4* __restrict__ out, int n4) {
    int i = blockIdx.x * blockDim.x + threadIdx.x;
    int stride = gridDim.x * blockDim.x;
    for (; i < n4; i += stride) {
        float4 v = in[i];
        ushort4 o;
        o.x = f2bf(v.x); o.y = f2bf(v.y); o.z = f2bf(v.z); o.w = f2bf(v.w);
        out[i] = o;
    }
}

// ---------------- pack W1,W2 into MFMA B-fragment order; zero gcnt ----------
// frag(s,n), lane l, j=0..7:  B[k = s*32 + (l>>4)*8 + j][c = n*16 + (l&15)]
__global__ __launch_bounds__(256) void wprep2(const float* __restrict__ W1,
                                              const float* __restrict__ W2,
                                              unsigned short* __restrict__ Wf1,
                                              unsigned short* __restrict__ Wf2,
                                              int* __restrict__ gcnt) {
    int id = blockIdx.x * 256 + threadIdx.x;  // 0..4095
    if (blockIdx.x == 0 && threadIdx.x < NB) gcnt[threadIdx.x] = 0;
    const float* W = (id < 2048) ? W1 : W2;
    unsigned short* Wf = (id < 2048) ? Wf1 : Wf2;
    id &= 2047;
    const int l = id & 63, nn = (id >> 6) & 7, s = id >> 9;
    const int c = nn * 16 + (l & 15);
    const int k0 = s * 32 + (l >> 4) * 8;
    ushort4 lo, hi;
    lo.x = f2bf(W[(k0 + 0) * F + c]); lo.y = f2bf(W[(k0 + 1) * F + c]);
    lo.z = f2bf(W[(k0 + 2) * F + c]); lo.w = f2bf(W[(k0 + 3) * F + c]);
    hi.x = f2bf(W[(k0 + 4) * F + c]); hi.y = f2bf(W[(k0 + 5) * F + c]);
    hi.z = f2bf(W[(k0 + 6) * F + c]); hi.w = f2bf(W[(k0 + 7) * F + c]);
    ushort4* p = (ushort4*)(Wf + (size_t)id * 8);
    p[0] = lo; p[1] = hi;
}

// ---------------- phase A: multi-split edges into 128 coarse buckets --------
// Single-atomic-pass: the histogram atomicAdd's return value IS the rank.
__global__ __launch_bounds__(256) void bucketA(const int* __restrict__ src,
                                               const int* __restrict__ dst,
                                               unsigned* __restrict__ E1,
                                               int* __restrict__ gcnt) {
    __shared__ unsigned hist[4][NB];
    __shared__ unsigned start[4][NB];
    const int t = threadIdx.x, w = t >> 6;
    for (int i = t; i < 4 * NB; i += 256) ((unsigned*)hist)[i] = 0;
    __syncthreads();
    const int base = blockIdx.x * (256 * EPT);
    unsigned rec[EPT]; int bkt[EPT]; unsigned rnk[EPT];
#pragma unroll
    for (int k = 0; k < EPT; ++k) {
        const int i = base + k * 256 + t;  // coalesced
        const int s = src[i], d = dst[i];
        const int b = d / BSH;             // const divide -> magic mul
        rec[k] = ((unsigned)s << 9) | (unsigned)(d - b * BSH);
        bkt[k] = b;
        rnk[k] = atomicAdd(&hist[w][b], 1u);
    }
    __syncthreads();
    if (t < NB) {
        const unsigned h0 = hist[0][t], h1 = hist[1][t], h2 = hist[2][t], h3 = hist[3][t];
        const unsigned tot = h0 + h1 + h2 + h3;
        const unsigned g = tot ? (unsigned)atomicAdd(&gcnt[t], (int)tot) : 0u;
        start[0][t] = g;
        start[1][t] = g + h0;
        start[2][t] = g + h0 + h1;
        start[3][t] = g + h0 + h1 + h2;
    }
    __syncthreads();
#pragma unroll
    for (int k = 0; k < EPT; ++k) {
        const unsigned p = start[w][bkt[k]] + rnk[k];
        if (p < BCAP) E1[(size_t)bkt[k] * BCAP + p] = rec[k];
    }
}

// ---------------- phase B: in-LDS counting sort per bucket -> exact CSR -----
__global__ __launch_bounds__(256) void bucketB(const unsigned* __restrict__ E1,
                                               const int* __restrict__ gcnt,
                                               int* __restrict__ off,
                                               unsigned short* __restrict__ ssrc) {
    __shared__ int cnt[BSH];
    __shared__ int cur[BSH];
    __shared__ int wtot[4];
    __shared__ int bst[NB];
    const int b = blockIdx.x, t = threadIdx.x;
    // one-wave exclusive scan of the 128 bucket counts
    if (t < 64) {
        const int a0 = gcnt[t * 2], a1 = gcnt[t * 2 + 1];
        const int s = a0 + a1;
        int inc = s;
#pragma unroll
        for (int o = 1; o <= 32; o <<= 1) {
            int u = __shfl_up(inc, o);
            if (t >= o) inc += u;
        }
        bst[t * 2] = inc - s;
        bst[t * 2 + 1] = inc - s + a0;
    }
    for (int i = t; i < BSH; i += 256) cnt[i] = 0;
    __syncthreads();
    const int ne = min(gcnt[b], BCAP);
    const int ebase = bst[b];
    const unsigned* E = E1 + (size_t)b * BCAP;
    for (int i = t; i < ne; i += 256) atomicAdd(&cnt[E[i] & 511], 1);
    __syncthreads();
    // exclusive scan of cnt[0..BSH), 2 elements per thread
    const int i0 = t * 2, i1 = t * 2 + 1;
    const int a0 = (i0 < BSH) ? cnt[i0] : 0;
    const int a1 = (i1 < BSH) ? cnt[i1] : 0;
    const int s = a0 + a1;
    int inc = s;
    const int lane = t & 63, w = t >> 6;
#pragma unroll
    for (int o = 1; o <= 32; o <<= 1) {
        int u = __shfl_up(inc, o);
        if (lane >= o) inc += u;
    }
    if (lane == 63) wtot[w] = inc;
    __syncthreads();
    int woff = 0;
    for (int k = 0; k < w; ++k) woff += wtot[k];  // w <= 3
    const int excl = woff + inc - s;
    if (i0 < BSH) {
        cur[i0] = excl;
        const int n = b * BSH + i0;
        if (n < NNODES) off[n] = ebase + excl;
    }
    if (i1 < BSH) {
        cur[i1] = excl + a0;
        const int n = b * BSH + i1;
        if (n < NNODES) off[n] = ebase + excl + a0;
    }
    if (b == NB - 1 && t == 0) off[NNODES] = NEDGES;
    __syncthreads();
    for (int i = t; i < ne; i += 256) {
        const unsigned rec = E[i];
        const int r = atomicAdd(&cur[rec & 511], 1);
        ssrc[ebase + r] = (unsigned short)(rec >> 9);
    }
}

// ---------------- FUSED agg + MLP: out = relu?((h + agg(h)) @ W + b) --------
// Wave handles 16 nodes (no barriers; wave-private LDS rows).
// Gather: 2 edges/wave (lane half h takes edge 2p+h, ushort4 = 4 feats/lane),
// combine halves via shfl_xor(32). Rows land in XOR-swizzled LDS
// (col_h ^= (row&7)<<3) -> A-frags read via b128 with ~2-way conflicts (free).
__global__ __launch_bounds__(256) void agg_mlp(const unsigned short* __restrict__ h,
                                               const int* __restrict__ off,
                                               const unsigned short* __restrict__ ssrc,
                                               const unsigned short* __restrict__ Wfrag,
                                               const float* __restrict__ bias,
                                               unsigned short* __restrict__ out,
                                               int n, int relu) {
    __shared__ unsigned short Sl[4][16][128];
    const int w = threadIdx.x >> 6, lane = threadIdx.x & 63;
    const int nbase = blockIdx.x * 64 + w * 16;
    const int half = lane >> 5, l32 = lane & 31;

    for (int m = 0; m < 16; ++m) {
        const int node = nbase + m;
        float a0 = 0.f, a1 = 0.f, a2 = 0.f, a3 = 0.f;
        if (node < n) {
            const int e0 = off[node], e1 = off[node + 1];
            if (half == 0) {  // self term once
                const ushort4 sv = *(const ushort4*)(h + (size_t)node * F + l32 * 4);
                a0 = b2f(sv.x); a1 = b2f(sv.y); a2 = b2f(sv.z); a3 = b2f(sv.w);
            }
            for (int eb = e0; eb < e1; eb += 64) {
                const int cnt = min(64, e1 - eb);
                const int myidx = (eb + lane < e1) ? (int)ssrc[eb + lane] : 0;
                int j = 0;
                for (; j + 8 <= cnt; j += 8) {  // 4 pairs in flight
                    const int s0 = __shfl(myidx, j + 0 + half);
                    const int s1 = __shfl(myidx, j + 2 + half);
                    const int s2 = __shfl(myidx, j + 4 + half);
                    const int s3 = __shfl(myidx, j + 6 + half);
                    const ushort4 v0 = *(const ushort4*)(h + (size_t)s0 * F + l32 * 4);
                    const ushort4 v1 = *(const ushort4*)(h + (size_t)s1 * F + l32 * 4);
                    const ushort4 v2 = *(const ushort4*)(h + (size_t)s2 * F + l32 * 4);
                    const ushort4 v3 = *(const ushort4*)(h + (size_t)s3 * F + l32 * 4);
                    a0 += (b2f(v0.x) + b2f(v1.x)) + (b2f(v2.x) + b2f(v3.x));
                    a1 += (b2f(v0.y) + b2f(v1.y)) + (b2f(v2.y) + b2f(v3.y));
                    a2 += (b2f(v0.z) + b2f(v1.z)) + (b2f(v2.z) + b2f(v3.z));
                    a3 += (b2f(v0.w) + b2f(v1.w)) + (b2f(v2.w) + b2f(v3.w));
                }
                for (; j < cnt; j += 2) {  // tail pairs (possibly half-empty)
                    const int s = __shfl(myidx, min(j + half, cnt - 1));
                    if (j + half < cnt) {
                        const ushort4 v = *(const ushort4*)(h + (size_t)s * F + l32 * 4);
                        a0 += b2f(v.x); a1 += b2f(v.y); a2 += b2f(v.z); a3 += b2f(v.w);
                    }
                }
            }
        }
        a0 += __shfl_xor(a0, 32); a1 += __shfl_xor(a1, 32);
        a2 += __shfl_xor(a2, 32); a3 += __shfl_xor(a3, 32);
        if (half == 0) {
            ushort4 wbv;
            wbv.x = f2bf(a0); wbv.y = f2bf(a1); wbv.z = f2bf(a2); wbv.w = f2bf(a3);
            *(ushort4*)(&Sl[w][m][(l32 * 4) ^ ((m & 7) << 3)]) = wbv;
        }
    }

    // --- MFMA phase: A from wave-private LDS rows, B from L2-hot Wfrag ---
    const int r16 = lane & 15, hi = lane >> 4;
    f32x4 acc[8];
#pragma unroll
    for (int i = 0; i < 8; ++i) acc[i] = (f32x4){0.f, 0.f, 0.f, 0.f};
#pragma unroll
    for (int s = 0; s < 4; ++s) {
        const bf16x8 a = *(const bf16x8*)(&Sl[w][r16][(s * 32 + hi * 8) ^ ((r16 & 7) << 3)]);
#pragma unroll
        for (int nn = 0; nn < 8; ++nn) {
            const bf16x8 b = *(const bf16x8*)(Wfrag + ((size_t)(s * 8 + nn) * 64 + lane) * 8);
            acc[nn] = __builtin_amdgcn_mfma_f32_16x16x32_bf16(a, b, acc[nn], 0, 0, 0);
        }
    }
#pragma unroll
    for (int nn = 0; nn < 8; ++nn) {
        const int col = nn * 16 + r16;
        const float bv = bias[col];
#pragma unroll
        for (int r = 0; r < 4; ++r) {
            const int row = nbase + hi * 4 + r;
            if (row < n) {
                float v = acc[nn][r] + bv;
                if (relu) v = fmaxf(v, 0.f);
                out[(size_t)row * F + col] = f2bf(v);
            }
        }
    }
}

// ---------------- layer-3 transform first (linearity): y = h @ W3 ----------
__global__ __launch_bounds__(256) void head_t(const unsigned short* __restrict__ Hb,
                                              const float4* __restrict__ W3,
                                              float2* __restrict__ y, int n) {
    const int wid = (blockIdx.x * blockDim.x + threadIdx.x) >> 6;
    const int lane = threadIdx.x & 63;
    if (wid >= n) return;
    const unsigned short* hp = Hb + (size_t)wid * F + lane * 2;
    const float hx = b2f(hp[0]), hy = b2f(hp[1]);
    const float4 w = W3[lane];
    float a0 = hx * w.x + hy * w.z;
    float a1 = hx * w.y + hy * w.w;
#pragma unroll
    for (int o = 32; o; o >>= 1) {
        a0 += __shfl_xor(a0, o);
        a1 += __shfl_xor(a1, o);
    }
    if (lane == 0) y[wid] = make_float2(a0, a1);
}

// ---------------- layer-3 aggregation on 2-dim y: out = y + agg(y) + b3 -----
__global__ __launch_bounds__(256) void agg3(const float2* __restrict__ y,
                                            const int* __restrict__ off,
                                            const unsigned short* __restrict__ ssrc,
                                            const float* __restrict__ b3,
                                            float2* __restrict__ out, int n) {
    const int i = blockIdx.x * blockDim.x + threadIdx.x;
    if (i >= n) return;
    float2 acc = y[i];
    const int e1 = off[i + 1];
    for (int e = off[i]; e < e1; ++e) {
        const float2 v = y[ssrc[e]];
        acc.x += v.x;
        acc.y += v.y;
    }
    out[i] = make_float2(acc.x + b3[0], acc.y + b3[1]);
}

extern "C" void kernel_launch(void* const* d_in, const int* in_sizes, int n_in,
                              void* d_out, int out_size, void* d_ws, size_t ws_size,
                              hipStream_t stream) {
    const float* x  = (const float*)d_in[0];
    const int* ei   = (const int*)d_in[1];
    const int* src  = ei;
    const int* dst  = ei + NEDGES;
    const float* W1 = (const float*)d_in[2];
    const float* b1 = (const float*)d_in[3];
    const float* W2 = (const float*)d_in[4];
    const float* b2 = (const float*)d_in[5];
    const float* W3 = (const float*)d_in[6];
    const float* b3 = (const float*)d_in[7];
    float* out = (float*)d_out;

    char* ws = (char*)d_ws;
    const size_t featB = (size_t)NNODES * F * 2;  // 12.8 MB
    unsigned short* xb = (unsigned short*)ws;                 // bf16 x; reused for H2
    unsigned short* Hb = (unsigned short*)(ws + featB);       // layer-1 output
    char* p = ws + 2 * featB;
    float* y3 = (float*)p;                 p += (size_t)NNODES * 2 * 4 + 256;
    unsigned short* Wf1 = (unsigned short*)p; p += 2048 * 8 * 2;
    unsigned short* Wf2 = (unsigned short*)p; p += 2048 * 8 * 2;
    unsigned* E1 = (unsigned*)p;           p += (size_t)NB * BCAP * 4;
    int* gcnt = (int*)p;                   p += NB * 4 + 256;
    int* off = (int*)p;                    p += (size_t)(NNODES + 1) * 4 + 256;
    unsigned short* ssrc = (unsigned short*)p;

    // ---- prep ----
    cvt_bf16<<<1024, 256, 0, stream>>>((const float4*)x, (ushort4*)xb, NNODES * F / 4);
    wprep2<<<16, 256, 0, stream>>>(W1, W2, Wf1, Wf2, gcnt);

    // ---- CSR build: bucketed two-phase counting sort ----
    bucketA<<<NEDGES / (256 * EPT), 256, 0, stream>>>(src, dst, E1, gcnt);
    bucketB<<<NB, 256, 0, stream>>>(E1, gcnt, off, ssrc);

    const int fusedBlocks = (NNODES + 63) / 64;  // 782

    // ---- layers 1 & 2 (fused agg+MLP) ----
    agg_mlp<<<fusedBlocks, 256, 0, stream>>>(xb, off, ssrc, Wf1, b1, Hb, NNODES, 1);
    agg_mlp<<<fusedBlocks, 256, 0, stream>>>(Hb, off, ssrc, Wf2, b2, xb, NNODES, 1);

    // ---- layer 3: transform first (linearity), then 2-dim aggregation ----
    head_t<<<(NNODES + 3) / 4, 256, 0, stream>>>(xb, (const float4*)W3, (float2*)y3, NNODES);
    agg3<<<(NNODES + 255) / 256, 256, 0, stream>>>((const float2*)y3, off, ssrc, b3, (float2*)out, NNODES);
}

// Round 8
// 314.140 us; speedup vs baseline: 1.0049x; 1.0049x over previous
//
#include <hip/hip_runtime.h>

#define NNODES 50000
#define NEDGES 1600000
#define F 128

#define NB 128        // coarse buckets
#define BSH 391       // nodes per bucket (128*391 = 50048 >= 50000)
#define BCAP 13312    // slots per bucket (mean 12500, +7 sigma)
#define EPT 10        // edges per thread in bucketA (625 * 2560 = 1600000 exactly)

typedef __attribute__((ext_vector_type(8))) short bf16x8;
typedef __attribute__((ext_vector_type(4))) float f32x4;

__device__ inline unsigned short f2bf(float f) {
    union { float f; unsigned u; } v; v.f = f;
    unsigned r = v.u + 0x7FFF + ((v.u >> 16) & 1);  // RNE
    return (unsigned short)(r >> 16);
}
__device__ inline float b2f(unsigned short h) {
    union { unsigned u; float f; } a;
    a.u = ((unsigned)h) << 16;
    return a.f;
}

// ---------------- f32 -> bf16 feature conversion ----------------
__global__ __launch_bounds__(256) void cvt_bf16(const float4* __restrict__ in,
                                                ushort4* __restrict__ out, int n4) {
    int i = blockIdx.x * blockDim.x + threadIdx.x;
    int stride = gridDim.x * blockDim.x;
    for (; i < n4; i += stride) {
        float4 v = in[i];
        ushort4 o;
        o.x = f2bf(v.x); o.y = f2bf(v.y); o.z = f2bf(v.z); o.w = f2bf(v.w);
        out[i] = o;
    }
}

// ---------------- pack W1,W2 into MFMA B-fragment order; zero gcnt ----------
// frag(s,n), lane l, j=0..7:  B[k = s*32 + (l>>4)*8 + j][c = n*16 + (l&15)]
__global__ __launch_bounds__(256) void wprep2(const float* __restrict__ W1,
                                              const float* __restrict__ W2,
                                              unsigned short* __restrict__ Wf1,
                                              unsigned short* __restrict__ Wf2,
                                              int* __restrict__ gcnt) {
    int id = blockIdx.x * 256 + threadIdx.x;  // 0..4095
    if (blockIdx.x == 0 && threadIdx.x < NB) gcnt[threadIdx.x] = 0;
    const float* W = (id < 2048) ? W1 : W2;
    unsigned short* Wf = (id < 2048) ? Wf1 : Wf2;
    id &= 2047;
    const int l = id & 63, nn = (id >> 6) & 7, s = id >> 9;
    const int c = nn * 16 + (l & 15);
    const int k0 = s * 32 + (l >> 4) * 8;
    ushort4 lo, hi;
    lo.x = f2bf(W[(k0 + 0) * F + c]); lo.y = f2bf(W[(k0 + 1) * F + c]);
    lo.z = f2bf(W[(k0 + 2) * F + c]); lo.w = f2bf(W[(k0 + 3) * F + c]);
    hi.x = f2bf(W[(k0 + 4) * F + c]); hi.y = f2bf(W[(k0 + 5) * F + c]);
    hi.z = f2bf(W[(k0 + 6) * F + c]); hi.w = f2bf(W[(k0 + 7) * F + c]);
    ushort4* p = (ushort4*)(Wf + (size_t)id * 8);
    p[0] = lo; p[1] = hi;
}

// ---------------- phase A: multi-split edges into 128 coarse buckets --------
// Single-atomic-pass: the histogram atomicAdd's return value IS the rank.
__global__ __launch_bounds__(256) void bucketA(const int* __restrict__ src,
                                               const int* __restrict__ dst,
                                               unsigned* __restrict__ E1,
                                               int* __restrict__ gcnt) {
    __shared__ unsigned hist[4][NB];
    __shared__ unsigned start[4][NB];
    const int t = threadIdx.x, w = t >> 6;
    for (int i = t; i < 4 * NB; i += 256) ((unsigned*)hist)[i] = 0;
    __syncthreads();
    const int base = blockIdx.x * (256 * EPT);
    unsigned rec[EPT]; int bkt[EPT]; unsigned rnk[EPT];
#pragma unroll
    for (int k = 0; k < EPT; ++k) {
        const int i = base + k * 256 + t;  // coalesced
        const int s = src[i], d = dst[i];
        const int b = d / BSH;             // const divide -> magic mul
        rec[k] = ((unsigned)s << 9) | (unsigned)(d - b * BSH);
        bkt[k] = b;
        rnk[k] = atomicAdd(&hist[w][b], 1u);
    }
    __syncthreads();
    if (t < NB) {
        const unsigned h0 = hist[0][t], h1 = hist[1][t], h2 = hist[2][t], h3 = hist[3][t];
        const unsigned tot = h0 + h1 + h2 + h3;
        const unsigned g = tot ? (unsigned)atomicAdd(&gcnt[t], (int)tot) : 0u;
        start[0][t] = g;
        start[1][t] = g + h0;
        start[2][t] = g + h0 + h1;
        start[3][t] = g + h0 + h1 + h2;
    }
    __syncthreads();
#pragma unroll
    for (int k = 0; k < EPT; ++k) {
        const unsigned p = start[w][bkt[k]] + rnk[k];
        if (p < BCAP) E1[(size_t)bkt[k] * BCAP + p] = rec[k];
    }
}

// ---------------- phase B: in-LDS counting sort per bucket -> exact CSR -----
__global__ __launch_bounds__(256) void bucketB(const unsigned* __restrict__ E1,
                                               const int* __restrict__ gcnt,
                                               int* __restrict__ off,
                                               unsigned short* __restrict__ ssrc) {
    __shared__ int cnt[BSH];
    __shared__ int cur[BSH];
    __shared__ int wtot[4];
    __shared__ int bst[NB];
    const int b = blockIdx.x, t = threadIdx.x;
    // one-wave exclusive scan of the 128 bucket counts
    if (t < 64) {
        const int a0 = gcnt[t * 2], a1 = gcnt[t * 2 + 1];
        const int s = a0 + a1;
        int inc = s;
#pragma unroll
        for (int o = 1; o <= 32; o <<= 1) {
            int u = __shfl_up(inc, o);
            if (t >= o) inc += u;
        }
        bst[t * 2] = inc - s;
        bst[t * 2 + 1] = inc - s + a0;
    }
    for (int i = t; i < BSH; i += 256) cnt[i] = 0;
    __syncthreads();
    const int ne = min(gcnt[b], BCAP);
    const int ebase = bst[b];
    const unsigned* E = E1 + (size_t)b * BCAP;
    for (int i = t; i < ne; i += 256) atomicAdd(&cnt[E[i] & 511], 1);
    __syncthreads();
    // exclusive scan of cnt[0..BSH), 2 elements per thread
    const int i0 = t * 2, i1 = t * 2 + 1;
    const int a0 = (i0 < BSH) ? cnt[i0] : 0;
    const int a1 = (i1 < BSH) ? cnt[i1] : 0;
    const int s = a0 + a1;
    int inc = s;
    const int lane = t & 63, w = t >> 6;
#pragma unroll
    for (int o = 1; o <= 32; o <<= 1) {
        int u = __shfl_up(inc, o);
        if (lane >= o) inc += u;
    }
    if (lane == 63) wtot[w] = inc;
    __syncthreads();
    int woff = 0;
    for (int k = 0; k < w; ++k) woff += wtot[k];  // w <= 3
    const int excl = woff + inc - s;
    if (i0 < BSH) {
        cur[i0] = excl;
        const int n = b * BSH + i0;
        if (n < NNODES) off[n] = ebase + excl;
    }
    if (i1 < BSH) {
        cur[i1] = excl + a0;
        const int n = b * BSH + i1;
        if (n < NNODES) off[n] = ebase + excl + a0;
    }
    if (b == NB - 1 && t == 0) off[NNODES] = NEDGES;
    __syncthreads();
    for (int i = t; i < ne; i += 256) {
        const unsigned rec = E[i];
        const int r = atomicAdd(&cur[rec & 511], 1);
        ssrc[ebase + r] = (unsigned short)(rec >> 9);
    }
}

// ---------------- FUSED agg + MLP v2: out = relu?((h + agg(h)) @ W + b) -----
// 1 wave per block, 16 nodes per wave. Each 32-lane HALF owns one node at a
// time (ushort4 = 4 feats/lane covers all 128) and walks its own edge list
// with 8 gathers in flight -> 16 outstanding loads/wave. Rows land in a
// 4 KB XOR-swizzled LDS tile; then the standard 32-MFMA block.
__global__ __launch_bounds__(64) void agg_mlp(const unsigned short* __restrict__ h,
                                              const int* __restrict__ off,
                                              const unsigned short* __restrict__ ssrc,
                                              const unsigned short* __restrict__ Wfrag,
                                              const float* __restrict__ bias,
                                              unsigned short* __restrict__ out,
                                              int n, int relu) {
    __shared__ unsigned short Sl[16][128];
    const int lane = threadIdx.x;
    const int nbase = blockIdx.x * 16;
    const int half = lane >> 5, l32 = lane & 31;

    for (int m = 0; m < 16; m += 2) {
        const int row = m + half;          // each half-wave owns one row
        const int node = nbase + row;
        float a0 = 0.f, a1 = 0.f, a2 = 0.f, a3 = 0.f;
        if (node < n) {
            const int e0 = off[node], e1 = off[node + 1];
            const ushort4 sv = *(const ushort4*)(h + (size_t)node * F + l32 * 4);
            a0 = b2f(sv.x); a1 = b2f(sv.y); a2 = b2f(sv.z); a3 = b2f(sv.w);
            for (int eb = e0; eb < e1; eb += 32) {
                const int cnt = min(32, e1 - eb);
                const int myidx = (eb + l32 < e1) ? (int)ssrc[eb + l32] : 0;
                int j = 0;
                for (; j + 8 <= cnt; j += 8) {  // 8 gathers in flight per half
                    const int s0 = __shfl(myidx, j + 0, 32);
                    const int s1 = __shfl(myidx, j + 1, 32);
                    const int s2 = __shfl(myidx, j + 2, 32);
                    const int s3 = __shfl(myidx, j + 3, 32);
                    const int s4 = __shfl(myidx, j + 4, 32);
                    const int s5 = __shfl(myidx, j + 5, 32);
                    const int s6 = __shfl(myidx, j + 6, 32);
                    const int s7 = __shfl(myidx, j + 7, 32);
                    const ushort4 v0 = *(const ushort4*)(h + (size_t)s0 * F + l32 * 4);
                    const ushort4 v1 = *(const ushort4*)(h + (size_t)s1 * F + l32 * 4);
                    const ushort4 v2 = *(const ushort4*)(h + (size_t)s2 * F + l32 * 4);
                    const ushort4 v3 = *(const ushort4*)(h + (size_t)s3 * F + l32 * 4);
                    const ushort4 v4 = *(const ushort4*)(h + (size_t)s4 * F + l32 * 4);
                    const ushort4 v5 = *(const ushort4*)(h + (size_t)s5 * F + l32 * 4);
                    const ushort4 v6 = *(const ushort4*)(h + (size_t)s6 * F + l32 * 4);
                    const ushort4 v7 = *(const ushort4*)(h + (size_t)s7 * F + l32 * 4);
                    a0 += ((b2f(v0.x) + b2f(v1.x)) + (b2f(v2.x) + b2f(v3.x))) +
                          ((b2f(v4.x) + b2f(v5.x)) + (b2f(v6.x) + b2f(v7.x)));
                    a1 += ((b2f(v0.y) + b2f(v1.y)) + (b2f(v2.y) + b2f(v3.y))) +
                          ((b2f(v4.y) + b2f(v5.y)) + (b2f(v6.y) + b2f(v7.y)));
                    a2 += ((b2f(v0.z) + b2f(v1.z)) + (b2f(v2.z) + b2f(v3.z))) +
                          ((b2f(v4.z) + b2f(v5.z)) + (b2f(v6.z) + b2f(v7.z)));
                    a3 += ((b2f(v0.w) + b2f(v1.w)) + (b2f(v2.w) + b2f(v3.w))) +
                          ((b2f(v4.w) + b2f(v5.w)) + (b2f(v6.w) + b2f(v7.w)));
                }
                for (; j < cnt; ++j) {
                    const int s = __shfl(myidx, j, 32);
                    const ushort4 v = *(const ushort4*)(h + (size_t)s * F + l32 * 4);
                    a0 += b2f(v.x); a1 += b2f(v.y); a2 += b2f(v.z); a3 += b2f(v.w);
                }
            }
        }
        ushort4 wbv;
        wbv.x = f2bf(a0); wbv.y = f2bf(a1); wbv.z = f2bf(a2); wbv.w = f2bf(a3);
        *(ushort4*)(&Sl[row][(l32 * 4) ^ ((row & 7) << 3)]) = wbv;
    }

    // --- MFMA phase: A from wave-private LDS rows, B from L2-hot Wfrag ---
    const int r16 = lane & 15, hi = lane >> 4;
    f32x4 acc[8];
#pragma unroll
    for (int i = 0; i < 8; ++i) acc[i] = (f32x4){0.f, 0.f, 0.f, 0.f};
#pragma unroll
    for (int s = 0; s < 4; ++s) {
        const bf16x8 a = *(const bf16x8*)(&Sl[r16][(s * 32 + hi * 8) ^ ((r16 & 7) << 3)]);
#pragma unroll
        for (int nn = 0; nn < 8; ++nn) {
            const bf16x8 b = *(const bf16x8*)(Wfrag + ((size_t)(s * 8 + nn) * 64 + lane) * 8);
            acc[nn] = __builtin_amdgcn_mfma_f32_16x16x32_bf16(a, b, acc[nn], 0, 0, 0);
        }
    }
#pragma unroll
    for (int nn = 0; nn < 8; ++nn) {
        const int col = nn * 16 + r16;
        const float bv = bias[col];
#pragma unroll
        for (int r = 0; r < 4; ++r) {
            const int row = nbase + hi * 4 + r;
            if (row < n) {
                float v = acc[nn][r] + bv;
                if (relu) v = fmaxf(v, 0.f);
                out[(size_t)row * F + col] = f2bf(v);
            }
        }
    }
}

// ---------------- layer-3 transform first (linearity): y = h @ W3 ----------
__global__ __launch_bounds__(256) void head_t(const unsigned short* __restrict__ Hb,
                                              const float4* __restrict__ W3,
                                              float2* __restrict__ y, int n) {
    const int wid = (blockIdx.x * blockDim.x + threadIdx.x) >> 6;
    const int lane = threadIdx.x & 63;
    if (wid >= n) return;
    const unsigned short* hp = Hb + (size_t)wid * F + lane * 2;
    const float hx = b2f(hp[0]), hy = b2f(hp[1]);
    const float4 w = W3[lane];
    float a0 = hx * w.x + hy * w.z;
    float a1 = hx * w.y + hy * w.w;
#pragma unroll
    for (int o = 32; o; o >>= 1) {
        a0 += __shfl_xor(a0, o);
        a1 += __shfl_xor(a1, o);
    }
    if (lane == 0) y[wid] = make_float2(a0, a1);
}

// ---------------- layer-3 aggregation on 2-dim y: out = y + agg(y) + b3 -----
__global__ __launch_bounds__(256) void agg3(const float2* __restrict__ y,
                                            const int* __restrict__ off,
                                            const unsigned short* __restrict__ ssrc,
                                            const float* __restrict__ b3,
                                            float2* __restrict__ out, int n) {
    const int i = blockIdx.x * blockDim.x + threadIdx.x;
    if (i >= n) return;
    float2 acc = y[i];
    const int e1 = off[i + 1];
    for (int e = off[i]; e < e1; ++e) {
        const float2 v = y[ssrc[e]];
        acc.x += v.x;
        acc.y += v.y;
    }
    out[i] = make_float2(acc.x + b3[0], acc.y + b3[1]);
}

extern "C" void kernel_launch(void* const* d_in, const int* in_sizes, int n_in,
                              void* d_out, int out_size, void* d_ws, size_t ws_size,
                              hipStream_t stream) {
    const float* x  = (const float*)d_in[0];
    const int* ei   = (const int*)d_in[1];
    const int* src  = ei;
    const int* dst  = ei + NEDGES;
    const float* W1 = (const float*)d_in[2];
    const float* b1 = (const float*)d_in[3];
    const float* W2 = (const float*)d_in[4];
    const float* b2 = (const float*)d_in[5];
    const float* W3 = (const float*)d_in[6];
    const float* b3 = (const float*)d_in[7];
    float* out = (float*)d_out;

    char* ws = (char*)d_ws;
    const size_t featB = (size_t)NNODES * F * 2;  // 12.8 MB
    unsigned short* xb = (unsigned short*)ws;                 // bf16 x; reused for H2
    unsigned short* Hb = (unsigned short*)(ws + featB);       // layer-1 output
    char* p = ws + 2 * featB;
    float* y3 = (float*)p;                 p += (size_t)NNODES * 2 * 4 + 256;
    unsigned short* Wf1 = (unsigned short*)p; p += 2048 * 8 * 2;
    unsigned short* Wf2 = (unsigned short*)p; p += 2048 * 8 * 2;
    unsigned* E1 = (unsigned*)p;           p += (size_t)NB * BCAP * 4;
    int* gcnt = (int*)p;                   p += NB * 4 + 256;
    int* off = (int*)p;                    p += (size_t)(NNODES + 1) * 4 + 256;
    unsigned short* ssrc = (unsigned short*)p;

    // ---- prep ----
    cvt_bf16<<<1024, 256, 0, stream>>>((const float4*)x, (ushort4*)xb, NNODES * F / 4);
    wprep2<<<16, 256, 0, stream>>>(W1, W2, Wf1, Wf2, gcnt);

    // ---- CSR build: bucketed two-phase counting sort ----
    bucketA<<<NEDGES / (256 * EPT), 256, 0, stream>>>(src, dst, E1, gcnt);
    bucketB<<<NB, 256, 0, stream>>>(E1, gcnt, off, ssrc);

    const int fusedBlocks = (NNODES + 15) / 16;  // 3125 one-wave blocks

    // ---- layers 1 & 2 (fused agg+MLP) ----
    agg_mlp<<<fusedBlocks, 64, 0, stream>>>(xb, off, ssrc, Wf1, b1, Hb, NNODES, 1);
    agg_mlp<<<fusedBlocks, 64, 0, stream>>>(Hb, off, ssrc, Wf2, b2, xb, NNODES, 1);

    // ---- layer 3: transform first (linearity), then 2-dim aggregation ----
    head_t<<<(NNODES + 3) / 4, 256, 0, stream>>>(xb, (const float4*)W3, (float2*)y3, NNODES);
    agg3<<<(NNODES + 255) / 256, 256, 0, stream>>>((const float2*)y3, off, ssrc, b3, (float2*)out, NNODES);
}

// Round 9
// 276.273 us; speedup vs baseline: 1.1426x; 1.1371x over previous
//
#include <hip/hip_runtime.h>

#define NNODES 50000
#define NEDGES 1600000
#define F 128

#define NB 256        // coarse buckets
#define BSH 196       // nodes per bucket (256*196 = 50176 >= 50000)
#define BCAP 6784     // slots per bucket (mean 6250, +6.7 sigma)
#define EPT 10        // edges per thread in bucketA (625 * 2560 = 1600000 exactly)

typedef __attribute__((ext_vector_type(8))) short bf16x8;
typedef __attribute__((ext_vector_type(4))) float f32x4;

__device__ inline unsigned short f2bf(float f) {
    union { float f; unsigned u; } v; v.f = f;
    unsigned r = v.u + 0x7FFF + ((v.u >> 16) & 1);  // RNE
    return (unsigned short)(r >> 16);
}
__device__ inline float2 up2(ushort2 h) {
    union { unsigned u; float f; } a, b;
    a.u = ((unsigned)h.x) << 16; b.u = ((unsigned)h.y) << 16;
    return make_float2(a.f, b.f);
}
__device__ inline float b2f(unsigned short h) {
    union { unsigned u; float f; } a;
    a.u = ((unsigned)h) << 16;
    return a.f;
}

// ---------------- f32 -> bf16 feature conversion ----------------
__global__ __launch_bounds__(256) void cvt_bf16(const float4* __restrict__ in,
                                                ushort4* __restrict__ out, int n4) {
    int i = blockIdx.x * blockDim.x + threadIdx.x;
    int stride = gridDim.x * blockDim.x;
    for (; i < n4; i += stride) {
        float4 v = in[i];
        ushort4 o;
        o.x = f2bf(v.x); o.y = f2bf(v.y); o.z = f2bf(v.z); o.w = f2bf(v.w);
        out[i] = o;
    }
}

// ---------------- pack W1,W2 into MFMA B-fragment order; zero gcnt ----------
// frag(s,n), lane l, j=0..7:  B[k = s*32 + (l>>4)*8 + j][c = n*16 + (l&15)]
__global__ __launch_bounds__(256) void wprep2(const float* __restrict__ W1,
                                              const float* __restrict__ W2,
                                              unsigned short* __restrict__ Wf1,
                                              unsigned short* __restrict__ Wf2,
                                              int* __restrict__ gcnt) {
    int id = blockIdx.x * 256 + threadIdx.x;  // 0..4095
    if (blockIdx.x == 0) gcnt[threadIdx.x] = 0;  // NB == 256
    const float* W = (id < 2048) ? W1 : W2;
    unsigned short* Wf = (id < 2048) ? Wf1 : Wf2;
    id &= 2047;
    const int l = id & 63, nn = (id >> 6) & 7, s = id >> 9;
    const int c = nn * 16 + (l & 15);
    const int k0 = s * 32 + (l >> 4) * 8;
    ushort4 lo, hi;
    lo.x = f2bf(W[(k0 + 0) * F + c]); lo.y = f2bf(W[(k0 + 1) * F + c]);
    lo.z = f2bf(W[(k0 + 2) * F + c]); lo.w = f2bf(W[(k0 + 3) * F + c]);
    hi.x = f2bf(W[(k0 + 4) * F + c]); hi.y = f2bf(W[(k0 + 5) * F + c]);
    hi.z = f2bf(W[(k0 + 6) * F + c]); hi.w = f2bf(W[(k0 + 7) * F + c]);
    ushort4* p = (ushort4*)(Wf + (size_t)id * 8);
    p[0] = lo; p[1] = hi;
}

// ---------------- phase A: multi-split edges into 256 coarse buckets --------
// rec = (src << 8) | (dst % BSH); bucket = dst / BSH.
// Single-atomic-pass per-wave LDS histograms; chunked global writes.
__global__ __launch_bounds__(256) void bucketA(const int* __restrict__ src,
                                               const int* __restrict__ dst,
                                               unsigned* __restrict__ E1,
                                               int* __restrict__ gcnt) {
    __shared__ unsigned hist[4][NB];
    __shared__ unsigned start[4][NB];
    const int t = threadIdx.x, w = t >> 6;
    for (int i = t; i < 4 * NB; i += 256) ((unsigned*)hist)[i] = 0;
    __syncthreads();
    const int base = blockIdx.x * (256 * EPT);
    unsigned rec[EPT]; int bkt[EPT]; unsigned rnk[EPT];
#pragma unroll
    for (int k = 0; k < EPT; ++k) {
        const int i = base + k * 256 + t;  // coalesced
        const int s = src[i], d = dst[i];
        const int b = d / BSH;             // const divide -> magic mul
        rec[k] = ((unsigned)s << 8) | (unsigned)(d - b * BSH);
        bkt[k] = b;
        rnk[k] = atomicAdd(&hist[w][b], 1u);
    }
    __syncthreads();
    {
        const unsigned h0 = hist[0][t], h1 = hist[1][t], h2 = hist[2][t], h3 = hist[3][t];
        const unsigned tot = h0 + h1 + h2 + h3;
        const unsigned g = tot ? (unsigned)atomicAdd(&gcnt[t], (int)tot) : 0u;
        start[0][t] = g;
        start[1][t] = g + h0;
        start[2][t] = g + h0 + h1;
        start[3][t] = g + h0 + h1 + h2;
    }
    __syncthreads();
#pragma unroll
    for (int k = 0; k < EPT; ++k) {
        const unsigned p = start[w][bkt[k]] + rnk[k];
        if (p < BCAP) E1[(size_t)bkt[k] * BCAP + p] = rec[k];
    }
}

// ---------------- phase B: in-LDS counting sort per bucket -> exact CSR -----
__global__ __launch_bounds__(256) void bucketB(const unsigned* __restrict__ E1,
                                               const int* __restrict__ gcnt,
                                               int* __restrict__ off,
                                               unsigned short* __restrict__ ssrc) {
    __shared__ int cnt[BSH];
    __shared__ int cur[BSH];
    __shared__ int wtot[4];
    __shared__ int bst[NB];
    const int b = blockIdx.x, t = threadIdx.x;
    // one-wave exclusive scan of the 256 bucket counts (4 per lane)
    if (t < 64) {
        const int a0 = gcnt[t * 4], a1 = gcnt[t * 4 + 1];
        const int a2 = gcnt[t * 4 + 2], a3 = gcnt[t * 4 + 3];
        const int s = a0 + a1 + a2 + a3;
        int inc = s;
#pragma unroll
        for (int o = 1; o <= 32; o <<= 1) {
            int u = __shfl_up(inc, o);
            if (t >= o) inc += u;
        }
        const int e = inc - s;
        bst[t * 4] = e;
        bst[t * 4 + 1] = e + a0;
        bst[t * 4 + 2] = e + a0 + a1;
        bst[t * 4 + 3] = e + a0 + a1 + a2;
    }
    for (int i = t; i < BSH; i += 256) cnt[i] = 0;
    __syncthreads();
    const int ne = min(gcnt[b], BCAP);
    const int ebase = bst[b];
    const unsigned* E = E1 + (size_t)b * BCAP;
    for (int i = t; i < ne; i += 256) atomicAdd(&cnt[E[i] & 255], 1);
    __syncthreads();
    // exclusive scan of cnt[0..BSH), 1 element per thread (BSH=196 < 256)
    const int val = (t < BSH) ? cnt[t] : 0;
    int inc = val;
    const int lane = t & 63, w = t >> 6;
#pragma unroll
    for (int o = 1; o <= 32; o <<= 1) {
        int u = __shfl_up(inc, o);
        if (lane >= o) inc += u;
    }
    if (lane == 63) wtot[w] = inc;
    __syncthreads();
    int woff = 0;
    for (int k = 0; k < w; ++k) woff += wtot[k];  // w <= 3
    const int excl = woff + inc - val;
    if (t < BSH) {
        cur[t] = excl;
        const int n = b * BSH + t;
        if (n < NNODES) off[n] = ebase + excl;
    }
    if (b == NB - 1 && t == 0) off[NNODES] = NEDGES;
    __syncthreads();
    for (int i = t; i < ne; i += 256) {
        const unsigned rec = E[i];
        const int r = atomicAdd(&cur[rec & 255], 1);
        ssrc[ebase + r] = (unsigned short)(rec >> 8);
    }
}

// ---------------- aggregation (bf16): S[i] = h[i] + sum h[ssrc[e]] ------
// One wave per node (1-wave blocks, grid = n). Lane l holds feats 2l,2l+1.
// Coalesced index load per 64 edges + shfl broadcast; 16 gathers in flight.
__global__ __launch_bounds__(64) void agg_bf16(const ushort2* __restrict__ h,
                                               const int* __restrict__ off,
                                               const unsigned short* __restrict__ ssrc,
                                               ushort2* __restrict__ S, int n) {
    const int wid = blockIdx.x;
    const int lane = threadIdx.x;
    const int e0 = off[wid], e1 = off[wid + 1];
    float2 acc = up2(h[(size_t)wid * 64 + lane]);
    for (int base = e0; base < e1; base += 64) {
        const int cnt = min(64, e1 - base);
        const int myidx = (base + lane < e1) ? (int)ssrc[base + lane] : 0;
        int i = 0;
        for (; i + 16 <= cnt; i += 16) {
            float2 v[16];
#pragma unroll
            for (int k = 0; k < 16; ++k) {
                const int s = __shfl(myidx, i + k);
                v[k] = up2(h[(size_t)s * 64 + lane]);
            }
            float x0 = 0.f, y0 = 0.f;
#pragma unroll
            for (int k = 0; k < 16; ++k) { x0 += v[k].x; y0 += v[k].y; }
            acc.x += x0; acc.y += y0;
        }
        for (; i + 4 <= cnt; i += 4) {
            const int s0 = __shfl(myidx, i + 0), s1 = __shfl(myidx, i + 1);
            const int s2 = __shfl(myidx, i + 2), s3 = __shfl(myidx, i + 3);
            const float2 v0 = up2(h[(size_t)s0 * 64 + lane]);
            const float2 v1 = up2(h[(size_t)s1 * 64 + lane]);
            const float2 v2 = up2(h[(size_t)s2 * 64 + lane]);
            const float2 v3 = up2(h[(size_t)s3 * 64 + lane]);
            acc.x += (v0.x + v1.x) + (v2.x + v3.x);
            acc.y += (v0.y + v1.y) + (v2.y + v3.y);
        }
        for (; i < cnt; ++i) {
            const int s = __shfl(myidx, i);
            const float2 v = up2(h[(size_t)s * 64 + lane]);
            acc.x += v.x;
            acc.y += v.y;
        }
    }
    ushort2 o;
    o.x = f2bf(acc.x); o.y = f2bf(acc.y);
    S[(size_t)wid * 64 + lane] = o;
}

// ---------------- MFMA MLP: Hb = relu?(Sb @ W + b)  [M=n, N=128, K=128] -----
__global__ __launch_bounds__(256) void mlp_mfma(const unsigned short* __restrict__ Sb,
                                                const unsigned short* __restrict__ Wfrag,
                                                const float* __restrict__ bias,
                                                unsigned short* __restrict__ Hb,
                                                int n, int relu) {
    const int wave = threadIdx.x >> 6, lane = threadIdx.x & 63;
    const int base = blockIdx.x * 64 + wave * 16;
    const int r16 = lane & 15, hi = lane >> 4;
    int arow = base + r16;
    if (arow >= n) arow = n - 1;  // clamp loads; stores masked below
    const unsigned short* Arow = Sb + (size_t)arow * F;

    f32x4 acc[8];
#pragma unroll
    for (int i = 0; i < 8; ++i) acc[i] = (f32x4){0.f, 0.f, 0.f, 0.f};

#pragma unroll
    for (int s = 0; s < 4; ++s) {
        const bf16x8 a = *(const bf16x8*)(Arow + s * 32 + hi * 8);
#pragma unroll
        for (int nn = 0; nn < 8; ++nn) {
            const bf16x8 b = *(const bf16x8*)(Wfrag + ((size_t)(s * 8 + nn) * 64 + lane) * 8);
            acc[nn] = __builtin_amdgcn_mfma_f32_16x16x32_bf16(a, b, acc[nn], 0, 0, 0);
        }
    }

#pragma unroll
    for (int nn = 0; nn < 8; ++nn) {
        const int col = nn * 16 + r16;
        const float bv = bias[col];
#pragma unroll
        for (int r = 0; r < 4; ++r) {
            const int row = base + hi * 4 + r;
            if (row < n) {
                float v = acc[nn][r] + bv;
                if (relu) v = fmaxf(v, 0.f);
                Hb[(size_t)row * F + col] = f2bf(v);
            }
        }
    }
}

// ---------------- layer-3 transform first (linearity): y = h @ W3 ----------
__global__ __launch_bounds__(256) void head_t(const unsigned short* __restrict__ Hb,
                                              const float4* __restrict__ W3,
                                              float2* __restrict__ y, int n) {
    const int wid = (blockIdx.x * blockDim.x + threadIdx.x) >> 6;
    const int lane = threadIdx.x & 63;
    if (wid >= n) return;
    const unsigned short* hp = Hb + (size_t)wid * F + lane * 2;
    const float hx = b2f(hp[0]), hy = b2f(hp[1]);
    const float4 w = W3[lane];
    float a0 = hx * w.x + hy * w.z;
    float a1 = hx * w.y + hy * w.w;
#pragma unroll
    for (int o = 32; o; o >>= 1) {
        a0 += __shfl_xor(a0, o);
        a1 += __shfl_xor(a1, o);
    }
    if (lane == 0) y[wid] = make_float2(a0, a1);
}

// ---------------- layer-3 aggregation on 2-dim y: out = y + agg(y) + b3 -----
__global__ __launch_bounds__(256) void agg3(const float2* __restrict__ y,
                                            const int* __restrict__ off,
                                            const unsigned short* __restrict__ ssrc,
                                            const float* __restrict__ b3,
                                            float2* __restrict__ out, int n) {
    const int i = blockIdx.x * blockDim.x + threadIdx.x;
    if (i >= n) return;
    float2 acc = y[i];
    const int e1 = off[i + 1];
    for (int e = off[i]; e < e1; ++e) {
        const float2 v = y[ssrc[e]];
        acc.x += v.x;
        acc.y += v.y;
    }
    out[i] = make_float2(acc.x + b3[0], acc.y + b3[1]);
}

extern "C" void kernel_launch(void* const* d_in, const int* in_sizes, int n_in,
                              void* d_out, int out_size, void* d_ws, size_t ws_size,
                              hipStream_t stream) {
    const float* x  = (const float*)d_in[0];
    const int* ei   = (const int*)d_in[1];
    const int* src  = ei;
    const int* dst  = ei + NEDGES;
    const float* W1 = (const float*)d_in[2];
    const float* b1 = (const float*)d_in[3];
    const float* W2 = (const float*)d_in[4];
    const float* b2 = (const float*)d_in[5];
    const float* W3 = (const float*)d_in[6];
    const float* b3 = (const float*)d_in[7];
    float* out = (float*)d_out;

    char* ws = (char*)d_ws;
    const size_t featB = (size_t)NNODES * F * 2;  // 12.8 MB
    unsigned short* xb = (unsigned short*)ws;                 // bf16 x; reused for H2
    unsigned short* Sb = (unsigned short*)(ws + featB);       // aggregated (bf16)
    unsigned short* Hb = (unsigned short*)(ws + 2 * featB);   // layer-1 output
    char* p = ws + 3 * featB;
    float* y3 = (float*)p;                 p += (size_t)NNODES * 2 * 4 + 256;
    unsigned short* Wf1 = (unsigned short*)p; p += 2048 * 8 * 2;
    unsigned short* Wf2 = (unsigned short*)p; p += 2048 * 8 * 2;
    unsigned* E1 = (unsigned*)p;           p += (size_t)NB * BCAP * 4;
    int* gcnt = (int*)p;                   p += NB * 4 + 256;
    int* off = (int*)p;                    p += (size_t)(NNODES + 1) * 4 + 256;
    unsigned short* ssrc = (unsigned short*)p;

    // ---- prep ----
    cvt_bf16<<<1024, 256, 0, stream>>>((const float4*)x, (ushort4*)xb, NNODES * F / 4);
    wprep2<<<16, 256, 0, stream>>>(W1, W2, Wf1, Wf2, gcnt);

    // ---- CSR build: bucketed two-phase counting sort ----
    bucketA<<<NEDGES / (256 * EPT), 256, 0, stream>>>(src, dst, E1, gcnt);
    bucketB<<<NB, 256, 0, stream>>>(E1, gcnt, off, ssrc);

    const int mlpBlocks = (NNODES + 63) / 64;

    // ---- layer 1 ----
    agg_bf16<<<NNODES, 64, 0, stream>>>((const ushort2*)xb, off, ssrc, (ushort2*)Sb, NNODES);
    mlp_mfma<<<mlpBlocks, 256, 0, stream>>>(Sb, Wf1, b1, Hb, NNODES, 1);

    // ---- layer 2 ----
    agg_bf16<<<NNODES, 64, 0, stream>>>((const ushort2*)Hb, off, ssrc, (ushort2*)Sb, NNODES);
    mlp_mfma<<<mlpBlocks, 256, 0, stream>>>(Sb, Wf2, b2, xb, NNODES, 1);

    // ---- layer 3: transform first (linearity), then 2-dim aggregation ----
    head_t<<<(NNODES + 3) / 4, 256, 0, stream>>>(xb, (const float4*)W3, (float2*)y3, NNODES);
    agg3<<<(NNODES + 255) / 256, 256, 0, stream>>>((const float2*)y3, off, ssrc, b3, (float2*)out, NNODES);
}

// Round 10
// 267.481 us; speedup vs baseline: 1.1802x; 1.0329x over previous
//
#include <hip/hip_runtime.h>

#define NNODES 50000
#define NEDGES 1600000
#define F 128

#define NB 512        // coarse buckets
#define BSH 98        // nodes per bucket (512*98 = 50176 >= 50000)
#define BCAP 3500     // slots per bucket (mean 3125, +6.7 sigma)
#define EPT 10        // edges per thread in bucketA (625 * 2560 = 1600000 exactly)

#define PREP_A 625    // bucketA blocks
#define PREP_CVT 512  // cvt blocks
#define PREP_W 16     // wprep blocks

typedef __attribute__((ext_vector_type(8))) short bf16x8;
typedef __attribute__((ext_vector_type(4))) float f32x4;

__device__ inline unsigned short f2bf(float f) {
    union { float f; unsigned u; } v; v.f = f;
    unsigned r = v.u + 0x7FFF + ((v.u >> 16) & 1);  // RNE
    return (unsigned short)(r >> 16);
}
__device__ inline float2 up2(ushort2 h) {
    union { unsigned u; float f; } a, b;
    a.u = ((unsigned)h.x) << 16; b.u = ((unsigned)h.y) << 16;
    return make_float2(a.f, b.f);
}
__device__ inline float b2f(unsigned short h) {
    union { unsigned u; float f; } a;
    a.u = ((unsigned)h) << 16;
    return a.f;
}

// ---------------- merged prep: bucketA | cvt_bf16 | wprep ----------------
// Roles by blockIdx.x:  [0,625) bucketA,  [625,1137) cvt,  [1137,1153) wprep.
// gcnt must be zeroed (hipMemsetAsync) before this kernel.
__global__ __launch_bounds__(256) void prep(const float* __restrict__ x,
                                            const int* __restrict__ src,
                                            const int* __restrict__ dst,
                                            const float* __restrict__ W1,
                                            const float* __restrict__ W2,
                                            unsigned short* __restrict__ xb,
                                            unsigned short* __restrict__ Wf1,
                                            unsigned short* __restrict__ Wf2,
                                            unsigned* __restrict__ E1,
                                            int* __restrict__ gcnt) {
    const int bid = blockIdx.x;
    const int t = threadIdx.x;
    if (bid < PREP_A) {
        // ---- bucketA: multi-split edges into 512 coarse buckets ----
        // rec = (src << 7) | (dst % BSH); bucket = dst / BSH.
        __shared__ unsigned hist[4][NB];
        __shared__ unsigned start[4][NB];
        const int w = t >> 6;
        for (int i = t; i < 4 * NB; i += 256) ((unsigned*)hist)[i] = 0;
        __syncthreads();
        const int base = bid * (256 * EPT);
        unsigned rec[EPT]; int bkt[EPT]; unsigned rnk[EPT];
#pragma unroll
        for (int k = 0; k < EPT; ++k) {
            const int i = base + k * 256 + t;  // coalesced
            const int s = src[i], d = dst[i];
            const int b = d / BSH;             // const divide -> magic mul
            rec[k] = ((unsigned)s << 7) | (unsigned)(d - b * BSH);
            bkt[k] = b;
            rnk[k] = atomicAdd(&hist[w][b], 1u);
        }
        __syncthreads();
        for (int b = t; b < NB; b += 256) {
            const unsigned h0 = hist[0][b], h1 = hist[1][b], h2 = hist[2][b], h3 = hist[3][b];
            const unsigned tot = h0 + h1 + h2 + h3;
            const unsigned g = tot ? (unsigned)atomicAdd(&gcnt[b], (int)tot) : 0u;
            start[0][b] = g;
            start[1][b] = g + h0;
            start[2][b] = g + h0 + h1;
            start[3][b] = g + h0 + h1 + h2;
        }
        __syncthreads();
#pragma unroll
        for (int k = 0; k < EPT; ++k) {
            const unsigned p = start[w][bkt[k]] + rnk[k];
            if (p < BCAP) E1[(size_t)bkt[k] * BCAP + p] = rec[k];
        }
    } else if (bid < PREP_A + PREP_CVT) {
        // ---- cvt: f32 -> bf16 feature conversion ----
        const int n4 = NNODES * F / 4;
        const float4* in = (const float4*)x;
        ushort4* out = (ushort4*)xb;
        int i = (bid - PREP_A) * 256 + t;
        const int stride = PREP_CVT * 256;
        for (; i < n4; i += stride) {
            float4 v = in[i];
            ushort4 o;
            o.x = f2bf(v.x); o.y = f2bf(v.y); o.z = f2bf(v.z); o.w = f2bf(v.w);
            out[i] = o;
        }
    } else {
        // ---- wprep: pack W1,W2 into MFMA B-fragment order ----
        int id = (bid - PREP_A - PREP_CVT) * 256 + t;  // 0..4095
        const float* W = (id < 2048) ? W1 : W2;
        unsigned short* Wf = (id < 2048) ? Wf1 : Wf2;
        id &= 2047;
        const int l = id & 63, nn = (id >> 6) & 7, s = id >> 9;
        const int c = nn * 16 + (l & 15);
        const int k0 = s * 32 + (l >> 4) * 8;
        ushort4 lo, hi;
        lo.x = f2bf(W[(k0 + 0) * F + c]); lo.y = f2bf(W[(k0 + 1) * F + c]);
        lo.z = f2bf(W[(k0 + 2) * F + c]); lo.w = f2bf(W[(k0 + 3) * F + c]);
        hi.x = f2bf(W[(k0 + 4) * F + c]); hi.y = f2bf(W[(k0 + 5) * F + c]);
        hi.z = f2bf(W[(k0 + 6) * F + c]); hi.w = f2bf(W[(k0 + 7) * F + c]);
        ushort4* p = (ushort4*)(Wf + (size_t)id * 8);
        p[0] = lo; p[1] = hi;
    }
}

// ---------------- phase B: in-LDS counting sort per bucket -> exact CSR -----
__global__ __launch_bounds__(256) void bucketB(const unsigned* __restrict__ E1,
                                               const int* __restrict__ gcnt,
                                               int* __restrict__ off,
                                               unsigned short* __restrict__ ssrc) {
    __shared__ int cnt[BSH];
    __shared__ int cur[BSH];
    __shared__ int wtot[4];
    __shared__ int bst[NB];
    const int b = blockIdx.x, t = threadIdx.x;
    // one-wave exclusive scan of the 512 bucket counts (8 per lane)
    if (t < 64) {
        int a[8]; int s = 0;
#pragma unroll
        for (int k = 0; k < 8; ++k) { a[k] = gcnt[t * 8 + k]; s += a[k]; }
        int inc = s;
#pragma unroll
        for (int o = 1; o <= 32; o <<= 1) {
            int u = __shfl_up(inc, o);
            if (t >= o) inc += u;
        }
        int e = inc - s;
#pragma unroll
        for (int k = 0; k < 8; ++k) { bst[t * 8 + k] = e; e += a[k]; }
    }
    for (int i = t; i < BSH; i += 256) cnt[i] = 0;
    __syncthreads();
    const int ne = min(gcnt[b], BCAP);
    const int ebase = bst[b];
    const unsigned* E = E1 + (size_t)b * BCAP;
    for (int i = t; i < ne; i += 256) atomicAdd(&cnt[E[i] & 127], 1);
    __syncthreads();
    // exclusive scan of cnt[0..BSH), 1 element per thread (BSH=98 < 256)
    const int val = (t < BSH) ? cnt[t] : 0;
    int inc = val;
    const int lane = t & 63, w = t >> 6;
#pragma unroll
    for (int o = 1; o <= 32; o <<= 1) {
        int u = __shfl_up(inc, o);
        if (lane >= o) inc += u;
    }
    if (lane == 63) wtot[w] = inc;
    __syncthreads();
    int woff = 0;
    for (int k = 0; k < w; ++k) woff += wtot[k];  // w <= 3
    const int excl = woff + inc - val;
    if (t < BSH) {
        cur[t] = excl;
        const int n = b * BSH + t;
        if (n < NNODES) off[n] = ebase + excl;
    }
    if (b == NB - 1 && t == 0) off[NNODES] = NEDGES;
    __syncthreads();
    for (int i = t; i < ne; i += 256) {
        const unsigned rec = E[i];
        const int r = atomicAdd(&cur[rec & 127], 1);
        ssrc[ebase + r] = (unsigned short)(rec >> 7);
    }
}

// ---------------- aggregation (bf16): S[i] = h[i] + sum h[ssrc[e]] ------
// One wave per node (1-wave blocks, grid = n). Lane l holds feats 2l,2l+1.
// Coalesced index load per 64 edges + shfl broadcast; 16 gathers in flight.
__global__ __launch_bounds__(64) void agg_bf16(const ushort2* __restrict__ h,
                                               const int* __restrict__ off,
                                               const unsigned short* __restrict__ ssrc,
                                               ushort2* __restrict__ S, int n) {
    const int wid = blockIdx.x;
    const int lane = threadIdx.x;
    const int e0 = off[wid], e1 = off[wid + 1];
    float2 acc = up2(h[(size_t)wid * 64 + lane]);
    for (int base = e0; base < e1; base += 64) {
        const int cnt = min(64, e1 - base);
        const int myidx = (base + lane < e1) ? (int)ssrc[base + lane] : 0;
        int i = 0;
        for (; i + 16 <= cnt; i += 16) {
            float2 v[16];
#pragma unroll
            for (int k = 0; k < 16; ++k) {
                const int s = __shfl(myidx, i + k);
                v[k] = up2(h[(size_t)s * 64 + lane]);
            }
            float x0 = 0.f, y0 = 0.f;
#pragma unroll
            for (int k = 0; k < 16; ++k) { x0 += v[k].x; y0 += v[k].y; }
            acc.x += x0; acc.y += y0;
        }
        for (; i + 4 <= cnt; i += 4) {
            const int s0 = __shfl(myidx, i + 0), s1 = __shfl(myidx, i + 1);
            const int s2 = __shfl(myidx, i + 2), s3 = __shfl(myidx, i + 3);
            const float2 v0 = up2(h[(size_t)s0 * 64 + lane]);
            const float2 v1 = up2(h[(size_t)s1 * 64 + lane]);
            const float2 v2 = up2(h[(size_t)s2 * 64 + lane]);
            const float2 v3 = up2(h[(size_t)s3 * 64 + lane]);
            acc.x += (v0.x + v1.x) + (v2.x + v3.x);
            acc.y += (v0.y + v1.y) + (v2.y + v3.y);
        }
        for (; i < cnt; ++i) {
            const int s = __shfl(myidx, i);
            const float2 v = up2(h[(size_t)s * 64 + lane]);
            acc.x += v.x;
            acc.y += v.y;
        }
    }
    ushort2 o;
    o.x = f2bf(acc.x); o.y = f2bf(acc.y);
    S[(size_t)wid * 64 + lane] = o;
}

// ---------------- MFMA MLP: Hb = relu?(Sb @ W + b)  [M=n, N=128, K=128] -----
__global__ __launch_bounds__(256) void mlp_mfma(const unsigned short* __restrict__ Sb,
                                                const unsigned short* __restrict__ Wfrag,
                                                const float* __restrict__ bias,
                                                unsigned short* __restrict__ Hb,
                                                int n, int relu) {
    const int wave = threadIdx.x >> 6, lane = threadIdx.x & 63;
    const int base = blockIdx.x * 64 + wave * 16;
    const int r16 = lane & 15, hi = lane >> 4;
    int arow = base + r16;
    if (arow >= n) arow = n - 1;  // clamp loads; stores masked below
    const unsigned short* Arow = Sb + (size_t)arow * F;

    f32x4 acc[8];
#pragma unroll
    for (int i = 0; i < 8; ++i) acc[i] = (f32x4){0.f, 0.f, 0.f, 0.f};

#pragma unroll
    for (int s = 0; s < 4; ++s) {
        const bf16x8 a = *(const bf16x8*)(Arow + s * 32 + hi * 8);
#pragma unroll
        for (int nn = 0; nn < 8; ++nn) {
            const bf16x8 b = *(const bf16x8*)(Wfrag + ((size_t)(s * 8 + nn) * 64 + lane) * 8);
            acc[nn] = __builtin_amdgcn_mfma_f32_16x16x32_bf16(a, b, acc[nn], 0, 0, 0);
        }
    }

#pragma unroll
    for (int nn = 0; nn < 8; ++nn) {
        const int col = nn * 16 + r16;
        const float bv = bias[col];
#pragma unroll
        for (int r = 0; r < 4; ++r) {
            const int row = base + hi * 4 + r;
            if (row < n) {
                float v = acc[nn][r] + bv;
                if (relu) v = fmaxf(v, 0.f);
                Hb[(size_t)row * F + col] = f2bf(v);
            }
        }
    }
}

// ---------------- layer-3 transform first (linearity): y = h @ W3 ----------
__global__ __launch_bounds__(256) void head_t(const unsigned short* __restrict__ Hb,
                                              const float4* __restrict__ W3,
                                              float2* __restrict__ y, int n) {
    const int wid = (blockIdx.x * blockDim.x + threadIdx.x) >> 6;
    const int lane = threadIdx.x & 63;
    if (wid >= n) return;
    const unsigned short* hp = Hb + (size_t)wid * F + lane * 2;
    const float hx = b2f(hp[0]), hy = b2f(hp[1]);
    const float4 w = W3[lane];
    float a0 = hx * w.x + hy * w.z;
    float a1 = hx * w.y + hy * w.w;
#pragma unroll
    for (int o = 32; o; o >>= 1) {
        a0 += __shfl_xor(a0, o);
        a1 += __shfl_xor(a1, o);
    }
    if (lane == 0) y[wid] = make_float2(a0, a1);
}

// ---------------- layer-3 aggregation on 2-dim y: out = y + agg(y) + b3 -----
__global__ __launch_bounds__(256) void agg3(const float2* __restrict__ y,
                                            const int* __restrict__ off,
                                            const unsigned short* __restrict__ ssrc,
                                            const float* __restrict__ b3,
                                            float2* __restrict__ out, int n) {
    const int i = blockIdx.x * blockDim.x + threadIdx.x;
    if (i >= n) return;
    float2 acc = y[i];
    const int e1 = off[i + 1];
    for (int e = off[i]; e < e1; ++e) {
        const float2 v = y[ssrc[e]];
        acc.x += v.x;
        acc.y += v.y;
    }
    out[i] = make_float2(acc.x + b3[0], acc.y + b3[1]);
}

extern "C" void kernel_launch(void* const* d_in, const int* in_sizes, int n_in,
                              void* d_out, int out_size, void* d_ws, size_t ws_size,
                              hipStream_t stream) {
    const float* x  = (const float*)d_in[0];
    const int* ei   = (const int*)d_in[1];
    const int* src  = ei;
    const int* dst  = ei + NEDGES;
    const float* W1 = (const float*)d_in[2];
    const float* b1 = (const float*)d_in[3];
    const float* W2 = (const float*)d_in[4];
    const float* b2 = (const float*)d_in[5];
    const float* W3 = (const float*)d_in[6];
    const float* b3 = (const float*)d_in[7];
    float* out = (float*)d_out;

    char* ws = (char*)d_ws;
    const size_t featB = (size_t)NNODES * F * 2;  // 12.8 MB
    unsigned short* xb = (unsigned short*)ws;                 // bf16 x; reused for H2
    unsigned short* Sb = (unsigned short*)(ws + featB);       // aggregated (bf16)
    unsigned short* Hb = (unsigned short*)(ws + 2 * featB);   // layer-1 output
    char* p = ws + 3 * featB;
    float* y3 = (float*)p;                 p += (size_t)NNODES * 2 * 4 + 256;
    unsigned short* Wf1 = (unsigned short*)p; p += 2048 * 8 * 2;
    unsigned short* Wf2 = (unsigned short*)p; p += 2048 * 8 * 2;
    unsigned* E1 = (unsigned*)p;           p += (size_t)NB * BCAP * 4;
    int* gcnt = (int*)p;                   p += NB * 4 + 256;
    int* off = (int*)p;                    p += (size_t)(NNODES + 1) * 4 + 256;
    unsigned short* ssrc = (unsigned short*)p;

    // ---- prep (gcnt must be zero before prep's bucketA role) ----
    hipMemsetAsync(gcnt, 0, NB * sizeof(int), stream);
    prep<<<PREP_A + PREP_CVT + PREP_W, 256, 0, stream>>>(x, src, dst, W1, W2,
                                                         xb, Wf1, Wf2, E1, gcnt);
    bucketB<<<NB, 256, 0, stream>>>(E1, gcnt, off, ssrc);

    const int mlpBlocks = (NNODES + 63) / 64;

    // ---- layer 1 ----
    agg_bf16<<<NNODES, 64, 0, stream>>>((const ushort2*)xb, off, ssrc, (ushort2*)Sb, NNODES);
    mlp_mfma<<<mlpBlocks, 256, 0, stream>>>(Sb, Wf1, b1, Hb, NNODES, 1);

    // ---- layer 2 ----
    agg_bf16<<<NNODES, 64, 0, stream>>>((const ushort2*)Hb, off, ssrc, (ushort2*)Sb, NNODES);
    mlp_mfma<<<mlpBlocks, 256, 0, stream>>>(Sb, Wf2, b2, xb, NNODES, 1);

    // ---- layer 3: transform first (linearity), then 2-dim aggregation ----
    head_t<<<(NNODES + 3) / 4, 256, 0, stream>>>(xb, (const float4*)W3, (float2*)y3, NNODES);
    agg3<<<(NNODES + 255) / 256, 256, 0, stream>>>((const float2*)y3, off, ssrc, b3, (float2*)out, NNODES);
}